// Round 1
// baseline (425.880 us; speedup 1.0000x reference)
//
#include <hip/hip_runtime.h>
#include <math.h>

// Row-normalize: out[row, :] = adj[row, :] / sum(adj[row, :]),
// with 1/0 or 1/inf -> 0 per the reference's isfinite guard.
// Shape: [2, 8, 2048, 2048] fp32 -> 32768 rows of 2048 floats.
//
// Memory-bound: 256 MiB read + 256 MiB write. One block per row; each
// thread holds its 8 elements in registers so every byte moves exactly
// once in each direction.

#define ROW_N 2048
#define BLOCK 256
// 2048 floats = 512 float4; 256 threads -> 2 float4 per thread.

__global__ __launch_bounds__(BLOCK) void normalizer_kernel(
    const float* __restrict__ adj, float* __restrict__ out) {
  const size_t row = blockIdx.x;
  const float4* __restrict__ src =
      reinterpret_cast<const float4*>(adj + row * (size_t)ROW_N);
  float4* __restrict__ dst = reinterpret_cast<float4*>(out + row * (size_t)ROW_N);

  const int t = threadIdx.x;

  // Load 8 floats (2x float4), coalesced: lane i hits f4[i] and f4[i+256].
  float4 v0 = src[t];
  float4 v1 = src[t + BLOCK];

  float local = (v0.x + v0.y) + (v0.z + v0.w) + (v1.x + v1.y) + (v1.z + v1.w);

  // 64-lane wave tree reduction.
  #pragma unroll
  for (int off = 32; off > 0; off >>= 1)
    local += __shfl_down(local, off, 64);

  __shared__ float wave_sums[BLOCK / 64];
  __shared__ float s_inv;
  if ((t & 63) == 0) wave_sums[t >> 6] = local;
  __syncthreads();

  if (t == 0) {
    float deg = (wave_sums[0] + wave_sums[1]) + (wave_sums[2] + wave_sums[3]);
    float inv = 1.0f / deg;
    if (!isfinite(inv)) inv = 0.0f;  // matches jnp.where(isfinite(inv), inv, 0)
    s_inv = inv;
  }
  __syncthreads();

  const float inv = s_inv;
  v0.x *= inv; v0.y *= inv; v0.z *= inv; v0.w *= inv;
  v1.x *= inv; v1.y *= inv; v1.z *= inv; v1.w *= inv;

  dst[t] = v0;
  dst[t + BLOCK] = v1;
}

extern "C" void kernel_launch(void* const* d_in, const int* in_sizes, int n_in,
                              void* d_out, int out_size, void* d_ws, size_t ws_size,
                              hipStream_t stream) {
  const float* adj = (const float*)d_in[0];
  float* out = (float*)d_out;
  const int rows = out_size / ROW_N;  // 2*8*2048 = 32768
  normalizer_kernel<<<rows, BLOCK, 0, stream>>>(adj, out);
}